// Round 1
// baseline (165.986 us; speedup 1.0000x reference)
//
#include <hip/hip_runtime.h>

// CARAFE forward: N=8, C=128, H=64, W=64, k=5, G=1, s=2.
// out[n,c,2h+p,2w+q] = sum_{i,j} feat[n,c,h+i-2,w+j-2] * masks[n,i*5+j,2h+p,2w+q]
//
// One wave per (n, h, 16-channel chunk). lane = low-res w (64 lanes = W).
// Each lane owns the 2x2 output quad for its low-res pixel -> 100 masks live
// in VGPRs across the channel loop; feature patch re-read per channel (L1).

#define KK 5
#define PAD 2
#define CIN 128
#define HH 64
#define WW 64
#define HO 128
#define WO 128
#define CC_PER_BLOCK 16

__global__ __launch_bounds__(64, 3)
void carafe_fwd(const float* __restrict__ feat,
                const float* __restrict__ masks,
                float* __restrict__ out) {
    const int lane = threadIdx.x;          // low-res w, 0..63
    const int h    = blockIdx.x;           // low-res h, 0..63
    const int c0   = blockIdx.y * CC_PER_BLOCK;
    const int n    = blockIdx.z;

    // ---- load the 25 x (2x2) mask quad into registers (50 coalesced float2) ----
    float2 m[KK * KK][2];
    const float* mbase = masks + (size_t)n * (KK * KK) * HO * WO;
    #pragma unroll
    for (int k = 0; k < KK * KK; ++k) {
        #pragma unroll
        for (int p = 0; p < 2; ++p) {
            m[k][p] = *(const float2*)(mbase + ((size_t)k * HO + (2 * h + p)) * WO + 2 * lane);
        }
    }

    const float* fbase = feat + ((size_t)n * CIN + c0) * HH * WW;
    float*       obase = out  + ((size_t)n * CIN + c0) * HO * WO;

    for (int cc = 0; cc < CC_PER_BLOCK; ++cc) {
        const float* f = fbase + (size_t)cc * HH * WW;
        float2 acc0 = make_float2(0.f, 0.f);   // ho = 2h
        float2 acc1 = make_float2(0.f, 0.f);   // ho = 2h+1

        #pragma unroll
        for (int i = 0; i < KK; ++i) {
            const int r = h + i - PAD;
            if (r < 0 || r >= HH) continue;    // wave-uniform; pad rows contribute 0
            const float* frow = f + r * WW;
            #pragma unroll
            for (int j = 0; j < KK; ++j) {
                const int col = lane + j - PAD;
                const float fv = ((unsigned)col < (unsigned)WW) ? frow[col] : 0.0f;
                const float2 m0 = m[i * KK + j][0];
                const float2 m1 = m[i * KK + j][1];
                acc0.x += fv * m0.x;  acc0.y += fv * m0.y;
                acc1.x += fv * m1.x;  acc1.y += fv * m1.y;
            }
        }

        float* orow = obase + (size_t)cc * HO * WO + (2 * h) * WO + 2 * lane;
        *(float2*)(orow)      = acc0;
        *(float2*)(orow + WO) = acc1;
    }
}

extern "C" void kernel_launch(void* const* d_in, const int* in_sizes, int n_in,
                              void* d_out, int out_size, void* d_ws, size_t ws_size,
                              hipStream_t stream) {
    const float* feat  = (const float*)d_in[0];
    const float* masks = (const float*)d_in[1];
    float* out = (float*)d_out;

    dim3 grid(HH, CIN / CC_PER_BLOCK, 8);   // (h, c-chunk, n) = (64, 8, 8)
    dim3 block(64);
    carafe_fwd<<<grid, block, 0, stream>>>(feat, masks, out);
}

// Round 2
// 146.395 us; speedup vs baseline: 1.1338x; 1.1338x over previous
//
#include <hip/hip_runtime.h>

// CARAFE forward: N=8, C=128, H=64, W=64, k=5, G=1, s=2.
// out[n,c,2h+p,2w+q] = sum_{i,j} feat[n,c,h+i-2,w+j-2] * masks[n,i*5+j,2h+p,2w+q]
//
// Round 2: occupancy fix. Block = 256 threads = 4 waves: (p, channel-halfchunk).
// Each wave: fixed output row ho=2h+p, lane = low-res w, 2 outputs (q=0,1) per
// channel, 8 channels. Masks (25 float2 = 50 VGPR) live in registers across
// the channel loop; feature patch re-read per channel (L1; p=0/p=1 waves share
// the same CU's L1). 16384 waves total vs 4096 before.

#define KK 5
#define PAD 2
#define CIN 128
#define HH 64
#define WW 64
#define HO 128
#define WO 128
#define CC_PER_WAVE 8

__global__ __launch_bounds__(256, 4)
void carafe_fwd(const float* __restrict__ feat,
                const float* __restrict__ masks,
                float* __restrict__ out) {
    const int lane = threadIdx.x & 63;     // low-res w, 0..63
    const int wid  = threadIdx.x >> 6;     // 0..3
    const int p    = wid & 1;              // sub-pixel row
    const int sub  = wid >> 1;             // channel half-chunk
    const int h    = blockIdx.x;           // low-res h, 0..63
    const int c0   = blockIdx.y * (2 * CC_PER_WAVE) + sub * CC_PER_WAVE;
    const int n    = blockIdx.z;
    const int ho   = 2 * h + p;

    // ---- 25 mask float2 (this wave's output row, both q) into registers ----
    float2 m[KK * KK];
    const float* mbase = masks + (size_t)n * (KK * KK) * HO * WO;
    #pragma unroll
    for (int k = 0; k < KK * KK; ++k) {
        m[k] = *(const float2*)(mbase + ((size_t)k * HO + ho) * WO + 2 * lane);
    }

    const float* fbase = feat + ((size_t)n * CIN + c0) * HH * WW;
    float*       obase = out  + ((size_t)n * CIN + c0) * HO * WO;

    #pragma unroll 2
    for (int cc = 0; cc < CC_PER_WAVE; ++cc) {
        const float* f = fbase + (size_t)cc * HH * WW;
        float2 acc = make_float2(0.f, 0.f);

        #pragma unroll
        for (int i = 0; i < KK; ++i) {
            const int r = h + i - PAD;
            if (r < 0 || r >= HH) continue;    // wave-uniform; pad rows are 0
            const float* frow = f + r * WW;
            #pragma unroll
            for (int j = 0; j < KK; ++j) {
                const int col = lane + j - PAD;
                const float fv = ((unsigned)col < (unsigned)WW) ? frow[col] : 0.0f;
                const float2 mk = m[i * KK + j];
                acc.x += fv * mk.x;
                acc.y += fv * mk.y;
            }
        }

        *(float2*)(obase + (size_t)cc * HO * WO + (size_t)ho * WO + 2 * lane) = acc;
    }
}

extern "C" void kernel_launch(void* const* d_in, const int* in_sizes, int n_in,
                              void* d_out, int out_size, void* d_ws, size_t ws_size,
                              hipStream_t stream) {
    const float* feat  = (const float*)d_in[0];
    const float* masks = (const float*)d_in[1];
    float* out = (float*)d_out;

    dim3 grid(HH, CIN / (2 * CC_PER_WAVE), 8);   // (h, c-group, n) = (64, 8, 8)
    dim3 block(256);
    carafe_fwd<<<grid, block, 0, stream>>>(feat, masks, out);
}

// Round 3
// 115.541 us; speedup vs baseline: 1.4366x; 1.2670x over previous
//
#include <hip/hip_runtime.h>

// CARAFE forward: N=8, C=128, H=64, W=64, k=5, G=1, s=2.
// out[n,c,2h+p,2w+q] = sum_{i,j} feat[n,c,h+i-2,w+j-2] * masks[n,i*5+j,2h+p,2w+q]
//
// Round 3: LDS-staged features with zero halo; p-merged waves (4 outputs/lane).
// Block = 128 threads = 2 waves, each wave owns 8 channels (all of p,q).
// Masks: 25 taps x 4 (p,q) = 100 floats in VGPRs, reused across 8 channels.
// Features: [16ch][5 rows][2+64+2] in LDS, halo pre-zeroed -> compute loop is
// pure ds_read(imm offset) + v_fmac, no bounds checks, no addressing VALU.

#define KK 5
#define PAD 2
#define CIN 128
#define HH 64
#define WW 64
#define HO 128
#define WO 128
#define CH_PER_BLOCK 16
#define CH_PER_WAVE 8
#define LDS_STRIDE 68   // 2 halo + 64 data + 2 halo

__global__ __launch_bounds__(128, 4)
void carafe_fwd(const float* __restrict__ feat,
                const float* __restrict__ masks,
                float* __restrict__ out) {
    __shared__ float lds[CH_PER_BLOCK][KK][LDS_STRIDE];

    const int tid  = threadIdx.x;
    const int lane = tid & 63;          // low-res w
    const int sub  = tid >> 6;          // 0..1 channel half
    const int h    = blockIdx.x;        // low-res h
    const int c0   = blockIdx.y * CH_PER_BLOCK;
    const int n    = blockIdx.z;

    // ---- masks first (independent of LDS; latency overlaps staging) ----
    // m[k][p] = float2 (q0,q1) at output row 2h+p, col 2*lane
    float2 m[KK * KK][2];
    const float* mbase = masks + (size_t)n * (KK * KK) * HO * WO
                               + (size_t)(2 * h) * WO + 2 * lane;
    #pragma unroll
    for (int k = 0; k < KK * KK; ++k) {
        m[k][0] = *(const float2*)(mbase + (size_t)k * HO * WO);
        m[k][1] = *(const float2*)(mbase + (size_t)k * HO * WO + WO);
    }

    // ---- zero the halo columns (0,1,66,67) of all 80 (ch,row) rows ----
    for (int it = tid; it < CH_PER_BLOCK * KK * 2; it += 128) {
        int rowid = it >> 1;            // ch*5 + r
        int side  = it & 1;
        float* dst = &lds[0][0][0] + rowid * LDS_STRIDE + side * (LDS_STRIDE - 2);
        *(float2*)dst = make_float2(0.f, 0.f);
    }

    // ---- stage features: 16 ch x 5 rows x 32 float2, coalesced ----
    const float* fnc = feat + ((size_t)n * CIN + c0) * HH * WW;
    #pragma unroll
    for (int t = 0; t < 20; ++t) {
        int idx = t * 128 + tid;        // 0..2559
        int ch  = idx / 160;            // const-div -> magic mul
        int rem = idx - ch * 160;
        int r   = rem >> 5;             // 0..4
        int c2  = rem & 31;             // float2 col
        int rr  = h - PAD + r;
        bool ok = (unsigned)rr < (unsigned)HH;
        int rc  = ok ? rr : 0;
        float2 v = *(const float2*)(fnc + ((size_t)ch * HH + rc) * WW + 2 * c2);
        if (!ok) v = make_float2(0.f, 0.f);
        *(float2*)(&lds[ch][r][2 + 2 * c2]) = v;
    }
    __syncthreads();

    // ---- compute: 8 channels, 4 outputs each, pure ds_read + fmac ----
    const int chb = sub * CH_PER_WAVE;
    float* obase = out + ((size_t)n * CIN + c0 + chb) * HO * WO
                       + (size_t)(2 * h) * WO + 2 * lane;

    #pragma unroll
    for (int cc = 0; cc < CH_PER_WAVE; ++cc) {
        float2 a0 = make_float2(0.f, 0.f);   // row 2h
        float2 a1 = make_float2(0.f, 0.f);   // row 2h+1

        #pragma unroll
        for (int i = 0; i < KK; ++i) {
            // feature col (lane + j - 2) lives at LDS index (lane + j)
            const float* row = &lds[chb + cc][i][lane];
            float f[KK];
            #pragma unroll
            for (int j = 0; j < KK; ++j) f[j] = row[j];
            #pragma unroll
            for (int j = 0; j < KK; ++j) {
                const float2 m0 = m[i * KK + j][0];
                const float2 m1 = m[i * KK + j][1];
                a0.x += f[j] * m0.x;  a0.y += f[j] * m0.y;
                a1.x += f[j] * m1.x;  a1.y += f[j] * m1.y;
            }
        }

        float* o = obase + (size_t)cc * HO * WO;
        *(float2*)(o)      = a0;
        *(float2*)(o + WO) = a1;
    }
}

extern "C" void kernel_launch(void* const* d_in, const int* in_sizes, int n_in,
                              void* d_out, int out_size, void* d_ws, size_t ws_size,
                              hipStream_t stream) {
    const float* feat  = (const float*)d_in[0];
    const float* masks = (const float*)d_in[1];
    float* out = (float*)d_out;

    dim3 grid(HH, CIN / CH_PER_BLOCK, 8);   // (h, c-group, n) = (64, 8, 8)
    dim3 block(128);
    carafe_fwd<<<grid, block, 0, stream>>>(feat, masks, out);
}

// Round 4
// 108.735 us; speedup vs baseline: 1.5265x; 1.0626x over previous
//
#include <hip/hip_runtime.h>

// CARAFE forward: N=8, C=128, H=64, W=64, k=5, G=1, s=2.
// out[n,c,2h+p,2w+q] = sum_{i,j} feat[n,c,h+i-2,w+j-2] * masks[n,i*5+j,2h+p,2w+q]
//
// Round 4: 256-thread blocks = 4 waves (p x channel-half); per-wave masks are
// 25 float2 = 50 VGPR, PINNED in registers via empty asm (round 2/3 showed the
// compiler otherwise re-loads them every channel iteration -> latency-bound).
// Features staged in LDS [16ch][5][4|64|4] with float4 writes; halo + zeroed
// out-of-range rows make the 25-tap inner loop branch-free ds_read + v_fmac.

#define KK 5
#define PAD 2
#define CIN 128
#define HH 64
#define WW 64
#define HO 128
#define WO 128
#define CH_PER_BLOCK 16
#define CH_PER_WAVE 8
#define LDS_STRIDE 72   // 4 pad | 64 data | 4 pad  (data starts 16B-aligned)

__global__ __launch_bounds__(256, 4)
void carafe_fwd(const float* __restrict__ feat,
                const float* __restrict__ masks,
                float* __restrict__ out) {
    __shared__ float lds[CH_PER_BLOCK][KK][LDS_STRIDE];   // 23040 B

    const int tid  = threadIdx.x;
    const int lane = tid & 63;          // low-res w
    const int wid  = tid >> 6;          // 0..3
    const int p    = wid & 1;           // sub-pixel output row
    const int sub  = wid >> 1;          // channel half
    const int h    = blockIdx.x;        // low-res h
    const int c0   = blockIdx.y * CH_PER_BLOCK;
    const int n    = blockIdx.z;
    const int ho   = 2 * h + p;

    // ---- this wave's 25 mask float2 (q0,q1 at row ho), kept in VGPRs ----
    float2 m[KK * KK];
    const float* mbase = masks + (size_t)n * (KK * KK) * HO * WO
                               + (size_t)ho * WO + 2 * lane;
    #pragma unroll
    for (int k = 0; k < KK * KK; ++k) {
        m[k] = *(const float2*)(mbase + (size_t)k * HO * WO);
    }
    #pragma unroll
    for (int k = 0; k < KK * KK; ++k) {
        asm volatile("" : "+v"(m[k].x), "+v"(m[k].y));   // pin: no remat/re-load
    }

    // ---- zero halo columns: lds[ch][r][2..3] and [68..69] ----
    {
        int it = tid;                    // 160 float2 writes, one pass
        if (it < CH_PER_BLOCK * KK * 2) {
            int rowid = it >> 1;
            int side  = it & 1;
            float* dst = &lds[0][0][0] + rowid * LDS_STRIDE + 2 + side * 66;
            *(float2*)dst = make_float2(0.f, 0.f);
        }
    }

    // ---- stage features: 16 ch x 5 rows x 16 float4, coalesced, zero-fill OOB rows ----
    const float* fnc = feat + ((size_t)n * CIN + c0) * HH * WW;
    #pragma unroll
    for (int t = 0; t < 5; ++t) {
        int idx = t * 256 + tid;        // 0..1279
        int ch  = idx / 80;             // 5*16 float4 per channel
        int rem = idx - ch * 80;
        int r   = rem >> 4;             // 0..4
        int c4  = rem & 15;             // float4 col
        int rr  = h - PAD + r;
        bool ok = (unsigned)rr < (unsigned)HH;
        int rc  = ok ? rr : 0;
        float4 v = *(const float4*)(fnc + ((size_t)ch * HH + rc) * WW + 4 * c4);
        if (!ok) v = make_float4(0.f, 0.f, 0.f, 0.f);
        *(float4*)(&lds[ch][r][4 + 4 * c4]) = v;
    }
    __syncthreads();

    // ---- compute: 8 channels x 25 taps x 2 outputs, branch-free ----
    const int chb = sub * CH_PER_WAVE;
    float* obase = out + ((size_t)n * CIN + c0 + chb) * HO * WO
                       + (size_t)ho * WO + 2 * lane;

    #pragma unroll
    for (int cc = 0; cc < CH_PER_WAVE; ++cc) {
        float2 acc = make_float2(0.f, 0.f);

        #pragma unroll
        for (int i = 0; i < KK; ++i) {
            // feature col (lane + j - 2) lives at LDS index 4 + lane + j - 2
            const float* row = &lds[chb + cc][i][2 + lane];
            float f[KK];
            #pragma unroll
            for (int j = 0; j < KK; ++j) f[j] = row[j];
            #pragma unroll
            for (int j = 0; j < KK; ++j) {
                const float2 mk = m[i * KK + j];
                acc.x += f[j] * mk.x;
                acc.y += f[j] * mk.y;
            }
        }

        *(float2*)(obase + (size_t)cc * HO * WO) = acc;
    }
}

extern "C" void kernel_launch(void* const* d_in, const int* in_sizes, int n_in,
                              void* d_out, int out_size, void* d_ws, size_t ws_size,
                              hipStream_t stream) {
    const float* feat  = (const float*)d_in[0];
    const float* masks = (const float*)d_in[1];
    float* out = (float*)d_out;

    dim3 grid(HH, CIN / CH_PER_BLOCK, 8);   // (h, c-group, n) = (64, 8, 8)
    dim3 block(256);
    carafe_fwd<<<grid, block, 0, stream>>>(feat, masks, out);
}